// Round 1
// 46.134 us; speedup vs baseline: 1.0017x; 1.0017x over previous
//
#include <hip/hip_runtime.h>

// Problem constants (fixed by the reference harness)
#define B_DIM   4
#define H_HEADS 16
#define G_DIM   (2 * H_HEADS)   // 32 channels (key heads then value heads)
#define N_TOK   2048
#define F_DIM   64
#define K_TAPS  5
#define P_HALF  2
#define M_VAR   (P_HALF + 1)    // 3 boundary variants
#define T_TOK   32              // tokens per wave (sliding window)
#define TOK_BLK 128             // tokens per block (4 waves x 32)

typedef float f4 __attribute__((ext_vector_type(4)));

// lgkmcnt(0) only: vmcnt=63 (bits 3:0 + 15:14), expcnt=7, lgkmcnt=0
#define WAIT_LGKM0() __builtin_amdgcn_s_waitcnt(0xC07F)

__global__ __launch_bounds__(256) void twiker_fused_kernel(
    const int*   __restrict__ ids,     // [B, N]
    const float* __restrict__ key,     // [B, H, N, F]
    const float* __restrict__ value,   // [B, H, N, F]
    const float* __restrict__ emb,     // [VOCAB, 2K]
    float*       __restrict__ out)     // [B, G, N, F, M]
{
    const int b     = blockIdx.z;
    const int g     = blockIdx.y;              // 0..31
    const int n_blk = blockIdx.x * TOK_BLK;
    const int tid   = threadIdx.x;
    const bool is_key = (g < H_HEADS);

    // per-token softmax weights: [token][m*5+k], padded to 16 floats
    __shared__ float wlds[TOK_BLK][16];
    // per-wave output staging: 4 tokens x 192 floats, global flat layout
    __shared__ float ostage[4][4 * F_DIM * M_VAR];

    const int wave = tid >> 6;
    const int f    = tid & 63;
    const int n0   = n_blk + wave * T_TOK;

    const float* src = is_key
        ? key   + ((size_t)(b * H_HEADS + g)           * N_TOK) * F_DIM
        : value + ((size_t)(b * H_HEADS + g - H_HEADS) * N_TOK) * F_DIM;

    // ---- issue the first 12 window rows BEFORE phase 1 ----
    // These loads are independent of the softmax weights, so their HBM
    // latency hides under the emb gather + softmax + __syncthreads of the
    // value blocks (and costs nothing for key blocks).
    // win[0..11]: rows n0-2 .. n0+9; win[12..15]: distance-2 prefetch slot.
    float win[16];
    #pragma unroll
    for (int j = 0; j < 12; ++j) {
        const int r = n0 - 2 + j;              // wave-uniform bounds -> s_cbranch
        win[j] = (r >= 0 && r < N_TOK) ? src[(size_t)r * F_DIM + f] : 0.0f;
    }

    // ---- phase 1 (value blocks only): per-token softmax weights -> LDS ----
    if (!is_key) {
        if (tid < TOK_BLK) {
            const int n  = n_blk + tid;
            const int id = ids[b * N_TOK + n];
            const float* ep = emb + (size_t)id * (2 * K_TAPS) + K_TAPS;
            const float e0 = ep[0], e1 = ep[1], e2 = ep[2], e3 = ep[3], e4 = ep[4];
            float wv[16];
            // m = 0: logits [e0,e1,e2,e3,e4]
            {
                float mx = fmaxf(fmaxf(fmaxf(e0, e1), fmaxf(e2, e3)), e4);
                float p0 = expf(e0 - mx), p1 = expf(e1 - mx), p2 = expf(e2 - mx);
                float p3 = expf(e3 - mx), p4 = expf(e4 - mx);
                float r  = 1.0f / (p0 + p1 + p2 + p3 + p4);
                wv[0] = p0 * r; wv[1] = p1 * r; wv[2] = p2 * r;
                wv[3] = p3 * r; wv[4] = p4 * r;
            }
            // m = 1: logits [0,e1,e2,e3,0]
            {
                float mx = fmaxf(fmaxf(fmaxf(e1, e2), e3), 0.0f);
                float pz = expf(0.0f - mx);
                float p1 = expf(e1 - mx), p2 = expf(e2 - mx), p3 = expf(e3 - mx);
                float r  = 1.0f / (2.0f * pz + p1 + p2 + p3);
                wv[5] = pz * r; wv[6] = p1 * r; wv[7] = p2 * r;
                wv[8] = p3 * r; wv[9] = pz * r;
            }
            // m = 2: logits [0,0,e2,0,0]
            {
                float mx = fmaxf(e2, 0.0f);
                float pc = expf(e2 - mx);
                float pz = expf(0.0f - mx);
                float r  = 1.0f / (pc + 4.0f * pz);
                float wo = pz * r;
                wv[10] = wo; wv[11] = wo; wv[12] = pc * r;
                wv[13] = wo; wv[14] = wo;
            }
            wv[15] = 0.0f;
            #pragma unroll
            for (int j = 0; j < 4; ++j)
                *(f4*)&wlds[tid][4 * j] = *(f4*)&wv[4 * j];
        }
        __syncthreads();
    }

    // ---- phase 2: sliding-window conv, one wave = 32 consecutive tokens ----
    float kw_c = 0.0f, kw_o = 0.0f;
    if (is_key) {
        const float pe = expf(-10.0f);
        const float r  = 1.0f / (1.0f + 4.0f * pe);
        kw_c = r; kw_o = pe * r;
    }

    float* ob     = out + ((size_t)(b * G_DIM + g) * N_TOK + n0) * (F_DIM * M_VAR);
    float* sstage = &ostage[wave][0];

    #pragma unroll
    for (int t4 = 0; t4 < T_TOK; t4 += 4) {
        // distance-2 prefetch: rows consumed two chunks from now stay in
        // flight across ~2 chunk-times (~700-1000 cyc), covering loaded HBM
        // latency instead of the ~1-chunk distance of the old depth-1 scheme.
        if (t4 + 8 < T_TOK) {
            #pragma unroll
            for (int j = 0; j < 4; ++j) {
                const int r = n0 + t4 + 10 + j;     // always >= 10
                win[12 + j] = (r < N_TOK) ? src[(size_t)r * F_DIM + f] : 0.0f;
            }
        }
        // compute 4 tokens from win[0..7], stage into LDS in flat layout
        #pragma unroll
        for (int tt = 0; tt < 4; ++tt) {
            float o0, o1, o2;
            if (is_key) {
                // identical weights for all 3 boundary variants
                const float s = win[tt] + win[tt + 1] + win[tt + 3] + win[tt + 4];
                o0 = fmaf(win[tt + 2], kw_c, s * kw_o);
                o1 = o0; o2 = o0;
            } else {
                float wv[16];
                const float* wr = &wlds[wave * T_TOK + t4 + tt][0];
                #pragma unroll
                for (int j = 0; j < 4; ++j)
                    *(f4*)&wv[4 * j] = *(const f4*)&wr[4 * j];
                o0 = 0.0f; o1 = 0.0f; o2 = 0.0f;
                #pragma unroll
                for (int k = 0; k < K_TAPS; ++k) {
                    o0 = fmaf(win[tt + k], wv[k],      o0);
                    o1 = fmaf(win[tt + k], wv[5 + k],  o1);
                    o2 = fmaf(win[tt + k], wv[10 + k], o2);
                }
            }
            const int sb = (tt * F_DIM + f) * M_VAR;   // stride-3: 2-way = free
            sstage[sb]     = o0;
            sstage[sb + 1] = o1;
            sstage[sb + 2] = o2;
        }
        // Fence: cross-lane LDS dataflow within the wave. wave_barrier stops
        // the compiler reordering the flush reads above the staging writes;
        // lgkmcnt(0) orders the LDS pipe without draining vmcnt (prefetch
        // stays in flight).
        __builtin_amdgcn_wave_barrier();
        WAIT_LGKM0();
        // flush chunk: 3 x 16B-aligned nontemporal dwordx4, fully coalesced
        float* gchunk = ob + (size_t)t4 * (F_DIM * M_VAR);
        #pragma unroll
        for (int s = 0; s < 3; ++s) {
            f4 v = *(const f4*)&sstage[s * 256 + 4 * f];
            __builtin_nontemporal_store(v, (f4*)&gchunk[s * 256 + 4 * f]);
        }
        // keep next iteration's staging writes below this iteration's reads
        __builtin_amdgcn_wave_barrier();
        // slide the window by 4 rows (register renaming after full unroll)
        #pragma unroll
        for (int j = 0; j < 12; ++j) win[j] = win[j + 4];
    }
}

extern "C" void kernel_launch(void* const* d_in, const int* in_sizes, int n_in,
                              void* d_out, int out_size, void* d_ws, size_t ws_size,
                              hipStream_t stream) {
    const int*   ids   = (const int*)  d_in[0];
    const float* key   = (const float*)d_in[1];
    const float* value = (const float*)d_in[2];
    const float* emb   = (const float*)d_in[3];
    float*       out   = (float*)      d_out;

    dim3 grid(N_TOK / TOK_BLK, G_DIM, B_DIM);   // 16 x 32 x 4 = 2048 blocks
    dim3 block(256);
    twiker_fused_kernel<<<grid, block, 0, stream>>>(ids, key, value, emb, out);
}

// Round 2
// 45.523 us; speedup vs baseline: 1.0151x; 1.0134x over previous
//
#include <hip/hip_runtime.h>

// Problem constants (fixed by the reference harness)
#define B_DIM   4
#define H_HEADS 16
#define G_DIM   (2 * H_HEADS)   // 32 channels (key heads then value heads)
#define N_TOK   2048
#define F_DIM   64
#define K_TAPS  5
#define P_HALF  2
#define M_VAR   (P_HALF + 1)    // 3 boundary variants
#define T_TOK   32              // tokens per wave (sliding window)
#define TOK_BLK 128             // tokens per block (4 waves x 32)

typedef float f4 __attribute__((ext_vector_type(4)));
typedef float f3 __attribute__((ext_vector_type(3)));
// f3 has natural alignment 16; output addresses are only 4B-aligned
// (lane offset = f*12 bytes), so lower the pointee alignment for stores.
typedef f3 f3a __attribute__((aligned(4)));

__global__ __launch_bounds__(256) void twiker_fused_kernel(
    const int*   __restrict__ ids,     // [B, N]
    const float* __restrict__ key,     // [B, H, N, F]
    const float* __restrict__ value,   // [B, H, N, F]
    const float* __restrict__ emb,     // [VOCAB, 2K]
    float*       __restrict__ out)     // [B, G, N, F, M]
{
    const int b     = blockIdx.z;
    const int g     = blockIdx.y;              // 0..31
    const int n_blk = blockIdx.x * TOK_BLK;
    const int tid   = threadIdx.x;
    const bool is_key = (g < H_HEADS);

    // per-token softmax weights: [token][m*5+k], padded to 16 floats
    __shared__ float wlds[TOK_BLK][16];

    const int wave = tid >> 6;
    const int f    = tid & 63;
    const int n0   = n_blk + wave * T_TOK;

    const float* src = is_key
        ? key   + ((size_t)(b * H_HEADS + g)           * N_TOK) * F_DIM
        : value + ((size_t)(b * H_HEADS + g - H_HEADS) * N_TOK) * F_DIM;

    // Issue the first 8 window rows BEFORE phase 1 — their HBM latency hides
    // under the emb gather + softmax + __syncthreads of the value blocks.
    float win[12];
    #pragma unroll
    for (int j = 0; j < 8; ++j) {
        const int r = n0 - 2 + j;              // wave-uniform bounds -> s_cbranch
        win[j] = (r >= 0 && r < N_TOK) ? src[(size_t)r * F_DIM + f] : 0.0f;
    }

    // ---- phase 1 (value blocks only): per-token softmax weights -> LDS ----
    if (!is_key) {
        if (tid < TOK_BLK) {
            const int n  = n_blk + tid;
            const int id = ids[b * N_TOK + n];
            const float* ep = emb + (size_t)id * (2 * K_TAPS) + K_TAPS;
            const float e0 = ep[0], e1 = ep[1], e2 = ep[2], e3 = ep[3], e4 = ep[4];
            float wv[16];
            // m = 0: logits [e0,e1,e2,e3,e4]
            {
                float mx = fmaxf(fmaxf(fmaxf(e0, e1), fmaxf(e2, e3)), e4);
                float p0 = expf(e0 - mx), p1 = expf(e1 - mx), p2 = expf(e2 - mx);
                float p3 = expf(e3 - mx), p4 = expf(e4 - mx);
                float r  = 1.0f / (p0 + p1 + p2 + p3 + p4);
                wv[0] = p0 * r; wv[1] = p1 * r; wv[2] = p2 * r;
                wv[3] = p3 * r; wv[4] = p4 * r;
            }
            // m = 1: logits [0,e1,e2,e3,0]
            {
                float mx = fmaxf(fmaxf(fmaxf(e1, e2), e3), 0.0f);
                float pz = expf(0.0f - mx);
                float p1 = expf(e1 - mx), p2 = expf(e2 - mx), p3 = expf(e3 - mx);
                float r  = 1.0f / (2.0f * pz + p1 + p2 + p3);
                wv[5] = pz * r; wv[6] = p1 * r; wv[7] = p2 * r;
                wv[8] = p3 * r; wv[9] = pz * r;
            }
            // m = 2: logits [0,0,e2,0,0]
            {
                float mx = fmaxf(e2, 0.0f);
                float pc = expf(e2 - mx);
                float pz = expf(0.0f - mx);
                float r  = 1.0f / (pc + 4.0f * pz);
                float wo = pz * r;
                wv[10] = wo; wv[11] = wo; wv[12] = pc * r;
                wv[13] = wo; wv[14] = wo;
            }
            wv[15] = 0.0f;
            #pragma unroll
            for (int j = 0; j < 4; ++j)
                *(f4*)&wlds[tid][4 * j] = *(f4*)&wv[4 * j];
        }
        __syncthreads();
    }

    // ---- phase 2: sliding-window conv, one wave = 32 consecutive tokens ----
    float kw_c = 0.0f, kw_o = 0.0f;
    if (is_key) {
        const float pe = expf(-10.0f);
        const float r  = 1.0f / (1.0f + 4.0f * pe);
        kw_c = r; kw_o = pe * r;
    }

    float* ob = out + ((size_t)(b * G_DIM + g) * N_TOK + n0) * (F_DIM * M_VAR);

    #pragma unroll
    for (int t4 = 0; t4 < T_TOK; t4 += 4) {
        // depth-1 prefetch of the next chunk's 4 rows (peeled on last iter)
        if (t4 + 4 < T_TOK) {
            #pragma unroll
            for (int j = 0; j < 4; ++j) {
                const int r = n0 + t4 + 6 + j;      // always >= 6
                win[8 + j] = (r < N_TOK) ? src[(size_t)r * F_DIM + f] : 0.0f;
            }
        }
        // compute 4 tokens from win[0..7]; store each lane's (o0,o1,o2)
        // triple directly as a 12B dwordx3. Lane f writes bytes [f*12,
        // f*12+12) of the token's 768B record -> the wave's store is one
        // fully contiguous 768B span, full-line coverage, no LDS transpose.
        #pragma unroll
        for (int tt = 0; tt < 4; ++tt) {
            float o0, o1, o2;
            if (is_key) {
                // identical weights for all 3 boundary variants
                const float s = win[tt] + win[tt + 1] + win[tt + 3] + win[tt + 4];
                o0 = fmaf(win[tt + 2], kw_c, s * kw_o);
                o1 = o0; o2 = o0;
            } else {
                float wv[16];
                const float* wr = &wlds[wave * T_TOK + t4 + tt][0];  // wave-uniform -> broadcast
                #pragma unroll
                for (int j = 0; j < 4; ++j)
                    *(f4*)&wv[4 * j] = *(const f4*)&wr[4 * j];
                o0 = 0.0f; o1 = 0.0f; o2 = 0.0f;
                #pragma unroll
                for (int k = 0; k < K_TAPS; ++k) {
                    o0 = fmaf(win[tt + k], wv[k],      o0);
                    o1 = fmaf(win[tt + k], wv[5 + k],  o1);
                    o2 = fmaf(win[tt + k], wv[10 + k], o2);
                }
            }
            f3 v = {o0, o1, o2};
            float* gp = ob + (size_t)(t4 + tt) * (F_DIM * M_VAR) + f * M_VAR;
            __builtin_nontemporal_store(v, (f3a*)gp);
        }
        // slide the window by 4 rows (register renaming after full unroll)
        #pragma unroll
        for (int j = 0; j < 8; ++j) win[j] = win[j + 4];
    }
}

extern "C" void kernel_launch(void* const* d_in, const int* in_sizes, int n_in,
                              void* d_out, int out_size, void* d_ws, size_t ws_size,
                              hipStream_t stream) {
    const int*   ids   = (const int*)  d_in[0];
    const float* key   = (const float*)d_in[1];
    const float* value = (const float*)d_in[2];
    const float* emb   = (const float*)d_in[3];
    float*       out   = (float*)      d_out;

    dim3 grid(N_TOK / TOK_BLK, G_DIM, B_DIM);   // 16 x 32 x 4 = 2048 blocks
    dim3 block(256);
    twiker_fused_kernel<<<grid, block, 0, stream>>>(ids, key, value, emb, out);
}